// Round 4
// baseline (554.399 us; speedup 1.0000x reference)
//
#include <hip/hip_runtime.h>
#include <hip/hip_bf16.h>

#define NFFT 8192
#define NH   4096
#define D    1024
#define NSEQ 4096
#define NDP  512
#define BATCH 4
#define NT   512
#define PI_D 3.14159265358979323846

// 16-pt DFT internal constants
#define C1 0.92387953251128675613f
#define S1 0.38268343236508977173f
#define RT 0.70710678118654752440f

__device__ __forceinline__ int SWZ(int i) { return i ^ ((i >> 4) & 15) ^ ((i >> 8) & 15); }

__device__ __forceinline__ float2 cadd(float2 a, float2 b){ return make_float2(a.x+b.x, a.y+b.y); }
__device__ __forceinline__ float2 csub(float2 a, float2 b){ return make_float2(a.x-b.x, a.y-b.y); }
__device__ __forceinline__ float2 cmul(float2 a, float2 w){ return make_float2(a.x*w.x - a.y*w.y, a.x*w.y + a.y*w.x); }
__device__ __forceinline__ float2 cmulc(float2 a, float2 w){ return make_float2(a.x*w.x + a.y*w.y, a.y*w.x - a.x*w.y); }

// digit-reversal for radices [2,16,16,16] DIF (radix-2 first, stride 4096)
__device__ __forceinline__ int drev16(int k) {
    return ((k & 1) << 12) | (((k >> 1) & 15) << 8) | (((k >> 5) & 15) << 4) | ((k >> 9) & 15);
}
// bank-aware bijection tid(9b) x it(3b) -> k in [0,4096)
__device__ __forceinline__ int kmap16(int tid, int it) {
    return ((tid >> 7) & 3) | (it << 2) | ((tid & 15) << 5) | (((tid >> 4) & 7) << 9);
}

__global__ __launch_bounds__(256) void wtab_init(float2* __restrict__ wtab) {
    int m = blockIdx.x * 256 + threadIdx.x;   // grid 16 -> 4096 entries
    double a = -2.0 * PI_D * (double)m / (double)NFFT;
    wtab[m] = make_float2((float)cos(a), (float)sin(a));
}

// One radix-16 pass over LDS. Thread owns 16 points at stride H within its group.
// Fwd:  read -> DFT16 -> *stage twiddle -> write.
// Inv:  read -> *conj stage twiddle -> IDFT16 -> write.
template<int H, bool TW, bool INV>
__device__ __forceinline__ void pass16(float2* zs, const float2* __restrict__ wt, int t) {
    int blk = t >> 8;
    int i0, tw1i;
    if (H == 256)      { int j = t & 255;                      i0 = blk*4096 + j;           tw1i = 2*j;  }
    else if (H == 16)  { int g = (t>>4) & 15; int j = t & 15;  i0 = blk*4096 + g*256 + j;   tw1i = 32*j; }
    else               { int g = t & 255;                      i0 = blk*4096 + g*16;        tw1i = 0;    }

    float2 w1, w2, w3, w4, w8, w12;
    if (TW) {
        w1 = wt[tw1i];
        w2 = cmul(w1, w1);  w3 = cmul(w2, w1);
        w4 = cmul(w2, w2);  w8 = cmul(w4, w4);  w12 = cmul(w8, w4);
    }

    float2 v[16];
    #pragma unroll
    for (int q = 0; q < 16; ++q) v[q] = zs[SWZ(i0 + H*q)];

    if (INV && TW) {
        v[1]=cmulc(v[1],w1);  v[2]=cmulc(v[2],w2);  v[3]=cmulc(v[3],w3);
        v[4]=cmulc(v[4],w4);  v[5]=cmulc(v[5],cmul(w4,w1));  v[6]=cmulc(v[6],cmul(w4,w2));  v[7]=cmulc(v[7],cmul(w4,w3));
        v[8]=cmulc(v[8],w8);  v[9]=cmulc(v[9],cmul(w8,w1));  v[10]=cmulc(v[10],cmul(w8,w2)); v[11]=cmulc(v[11],cmul(w8,w3));
        v[12]=cmulc(v[12],w12); v[13]=cmulc(v[13],cmul(w12,w1)); v[14]=cmulc(v[14],cmul(w12,w2)); v[15]=cmulc(v[15],cmul(w12,w3));
    }

    // layer 1: groups (v[i], v[i+4], v[i+8], v[i+12]); s[i][o]
    float2 s[4][4];
    #pragma unroll
    for (int i = 0; i < 4; ++i) {
        float2 z0=v[i], z1=v[i+4], z2=v[i+8], z3=v[i+12];
        float2 A=cadd(z0,z2), Cc=csub(z0,z2), B=cadd(z1,z3), Dd=csub(z1,z3);
        s[i][0] = cadd(A,B);
        s[i][2] = csub(A,B);
        if (!INV) { s[i][1] = make_float2(Cc.x+Dd.y, Cc.y-Dd.x);   // C - iD
                    s[i][3] = make_float2(Cc.x-Dd.y, Cc.y+Dd.x); } // C + iD
        else      { s[i][1] = make_float2(Cc.x-Dd.y, Cc.y+Dd.x);
                    s[i][3] = make_float2(Cc.x+Dd.y, Cc.y-Dd.x); }
    }
    // internal twiddles W16^{i*o} (conj for INV)
    if (!INV) {
        s[1][1]=cmul(s[1][1],make_float2(C1,-S1)); s[1][2]=cmul(s[1][2],make_float2(RT,-RT)); s[1][3]=cmul(s[1][3],make_float2(S1,-C1));
        s[2][1]=cmul(s[2][1],make_float2(RT,-RT)); s[2][2]=make_float2(s[2][2].y,-s[2][2].x); s[2][3]=cmul(s[2][3],make_float2(-RT,-RT));
        s[3][1]=cmul(s[3][1],make_float2(S1,-C1)); s[3][2]=cmul(s[3][2],make_float2(-RT,-RT)); s[3][3]=cmul(s[3][3],make_float2(-C1,S1));
    } else {
        s[1][1]=cmul(s[1][1],make_float2(C1,S1));  s[1][2]=cmul(s[1][2],make_float2(RT,RT));  s[1][3]=cmul(s[1][3],make_float2(S1,C1));
        s[2][1]=cmul(s[2][1],make_float2(RT,RT));  s[2][2]=make_float2(-s[2][2].y,s[2][2].x); s[2][3]=cmul(s[2][3],make_float2(-RT,RT));
        s[3][1]=cmul(s[3][1],make_float2(S1,C1));  s[3][2]=cmul(s[3][2],make_float2(-RT,RT)); s[3][3]=cmul(s[3][3],make_float2(-C1,-S1));
    }
    // layer 2: groups (s[0][o], s[1][o], s[2][o], s[3][o]) -> y[o + 4*r2]
    float2 y[16];
    #pragma unroll
    for (int o = 0; o < 4; ++o) {
        float2 z0=s[0][o], z1=s[1][o], z2=s[2][o], z3=s[3][o];
        float2 A=cadd(z0,z2), Cc=csub(z0,z2), B=cadd(z1,z3), Dd=csub(z1,z3);
        y[o]    = cadd(A,B);
        y[o+8]  = csub(A,B);
        if (!INV) { y[o+4]  = make_float2(Cc.x+Dd.y, Cc.y-Dd.x);
                    y[o+12] = make_float2(Cc.x-Dd.y, Cc.y+Dd.x); }
        else      { y[o+4]  = make_float2(Cc.x-Dd.y, Cc.y+Dd.x);
                    y[o+12] = make_float2(Cc.x+Dd.y, Cc.y-Dd.x); }
    }

    if (!INV && TW) {
        y[1]=cmul(y[1],w1);  y[2]=cmul(y[2],w2);  y[3]=cmul(y[3],w3);
        y[4]=cmul(y[4],w4);  y[5]=cmul(y[5],cmul(w4,w1));  y[6]=cmul(y[6],cmul(w4,w2));  y[7]=cmul(y[7],cmul(w4,w3));
        y[8]=cmul(y[8],w8);  y[9]=cmul(y[9],cmul(w8,w1));  y[10]=cmul(y[10],cmul(w8,w2)); y[11]=cmul(y[11],cmul(w8,w3));
        y[12]=cmul(y[12],w12); y[13]=cmul(y[13],cmul(w12,w1)); y[14]=cmul(y[14],cmul(w12,w2)); y[15]=cmul(y[15],cmul(w12,w3));
    }
    #pragma unroll
    for (int r = 0; r < 16; ++r) zs[SWZ(i0 + H*r)] = y[r];
}

// conv: per dp-pair block. Phase 0: t-spectrum into registers. Then loop b=0..3:
// fwd FFT of zero-padded x (radix-2 fused in load), untangle*mul, inv FFT,
// final radix-2 fused with store (only n<4096 needed).
template<int PACKED>
__global__ __launch_bounds__(NT, 4) void conv_kernel(float2* __restrict__ xP,
                                                     const float2* __restrict__ tP,
                                                     const float* __restrict__ xg,
                                                     const float* __restrict__ tg,
                                                     float* __restrict__ outg,
                                                     const float2* __restrict__ wt) {
    __shared__ float2 zs[NFFT];
    int t  = threadIdx.x;
    int dp = blockIdx.x;

    // ---- Phase 0: t spectrum ----
    if (PACKED) {
        const float2* ts = tP + (size_t)dp * NFFT;
        #pragma unroll
        for (int it = 0; it < 8; ++it) {
            int idx = t + it * NT;
            float2 v0 = ts[idx], v1 = ts[idx + NH];
            zs[SWZ(idx)]      = cadd(v0, v1);
            zs[SWZ(idx + NH)] = cmul(csub(v0, v1), wt[idx]);
        }
    } else {
        const float* tb = tg + 2 * dp;
        #pragma unroll
        for (int it = 0; it < 8; ++it) {
            int idx = t + it * NT;
            float2 v0 = *(const float2*)(tb + (size_t)idx * D);
            float2 v1 = *(const float2*)(tb + (size_t)(idx + NH) * D);
            zs[SWZ(idx)]      = cadd(v0, v1);
            zs[SWZ(idx + NH)] = cmul(csub(v0, v1), wt[idx]);
        }
    }
    __syncthreads();
    pass16<256, true,  false>(zs, wt, t); __syncthreads();
    pass16<16,  true,  false>(zs, wt, t); __syncthreads();
    pass16<1,   false, false>(zs, wt, t); __syncthreads();

    float2 T0r[8], T1r[8];
    float2 Tny = make_float2(0.f, 0.f);
    #pragma unroll
    for (int it = 0; it < 8; ++it) {
        int k  = kmap16(t, it);
        int p1 = drev16(k);
        int p2 = drev16((NFFT - k) & (NFFT - 1));
        float2 z1 = zs[SWZ(p1)], z2 = zs[SWZ(p2)];
        T0r[it] = make_float2(0.5f*(z1.x + z2.x), 0.5f*(z1.y - z2.y));
        T1r[it] = make_float2(0.5f*(z1.y + z2.y), 0.5f*(z2.x - z1.x));
    }
    if (t == 0) {   // Nyquist bin k=4096 at position drev16(4096)=8
        float2 zn = zs[SWZ(8)];
        Tny = make_float2(zn.x, zn.y);
    }

    const float sc = 1.0f / (float)NFFT;
    for (int b = 0; b < BATCH; ++b) {
        __syncthreads();   // protect zs against prior-phase readers
        float2* slab = PACKED ? (xP + ((size_t)dp * BATCH + b) * NSEQ) : nullptr;
        if (PACKED) {
            #pragma unroll
            for (int it = 0; it < 8; ++it) {
                int idx = t + it * NT;
                float2 v = slab[idx];
                zs[SWZ(idx)]      = v;                     // x + 0
                zs[SWZ(idx + NH)] = cmul(v, wt[idx]);      // (x - 0)*W^idx
            }
        } else {
            const float* xb = xg + (size_t)b * NSEQ * D + 2 * dp;
            #pragma unroll
            for (int it = 0; it < 8; ++it) {
                int idx = t + it * NT;
                float2 v = *(const float2*)(xb + (size_t)idx * D);
                zs[SWZ(idx)]      = v;
                zs[SWZ(idx + NH)] = cmul(v, wt[idx]);
            }
        }
        __syncthreads();
        pass16<256, true,  false>(zs, wt, t); __syncthreads();
        pass16<16,  true,  false>(zs, wt, t); __syncthreads();
        pass16<1,   false, false>(zs, wt, t); __syncthreads();

        // untangle * multiply * repack (in place, pairwise race-free)
        #pragma unroll
        for (int it = 0; it < 8; ++it) {
            int k  = kmap16(t, it);
            int p1 = drev16(k);
            int p2 = drev16((NFFT - k) & (NFFT - 1));
            float2 z1 = zs[SWZ(p1)], z2 = zs[SWZ(p2)];
            float2 T0 = T0r[it], T1 = T1r[it];
            float x0r = 0.5f*(z1.x + z2.x), x0i = 0.5f*(z1.y - z2.y);
            float x1r = 0.5f*(z1.y + z2.y), x1i = 0.5f*(z2.x - z1.x);
            float y0r = x0r*T0.x - x0i*T0.y, y0i = x0r*T0.y + x0i*T0.x;
            float y1r = x1r*T1.x - x1i*T1.y, y1i = x1r*T1.y + x1i*T1.x;
            zs[SWZ(p1)] = make_float2(y0r - y1i, y0i + y1r);
            zs[SWZ(p2)] = make_float2(y0r + y1i, y1r - y0i);
        }
        if (t == 0) {
            float2 zn = zs[SWZ(8)];
            zs[SWZ(8)] = make_float2(zn.x * Tny.x, zn.y * Tny.y);
        }
        __syncthreads();

        pass16<1,   false, true>(zs, wt, t); __syncthreads();
        pass16<16,  true,  true>(zs, wt, t); __syncthreads();
        pass16<256, true,  true>(zs, wt, t); __syncthreads();

        // final radix-2 (only n < 4096) fused with store
        if (PACKED) {
            #pragma unroll
            for (int it = 0; it < 8; ++it) {
                int n = t + it * NT;
                float2 a  = zs[SWZ(n)];
                float2 bb = zs[SWZ(n + NH)];
                float2 r  = cadd(a, cmulc(bb, wt[n]));
                slab[n] = make_float2(r.x * sc, r.y * sc);
            }
        } else {
            float* ob = outg + (size_t)b * NSEQ * D + 2 * dp;
            #pragma unroll
            for (int it = 0; it < 8; ++it) {
                int n = t + it * NT;
                float2 a  = zs[SWZ(n)];
                float2 bb = zs[SWZ(n + NH)];
                float2 r  = cadd(a, cmulc(bb, wt[n]));
                *(float2*)(ob + (size_t)n * D) = make_float2(r.x * sc, r.y * sc);
            }
        }
    }
}

// ---------- transpose/pack: (b,n,d) f32 -> (dp, b, n) float2 ----------
__global__ __launch_bounds__(256) void pack_kernel(const float* __restrict__ in,
                                                   float2* __restrict__ outp,
                                                   int Nrows, int Bsz) {
    __shared__ float tile[64][65];
    int tid = threadIdx.x;
    int n0 = blockIdx.x * 64;
    int d0 = blockIdx.y * 64;
    int b  = blockIdx.z;
    const float* ib = in + (size_t)b * Nrows * D;
    #pragma unroll
    for (int it = 0; it < 16; ++it) {
        int n_l = it * 4 + (tid >> 6);
        int d_l = tid & 63;
        tile[n_l][d_l] = ib[(size_t)(n0 + n_l) * D + d0 + d_l];
    }
    __syncthreads();
    #pragma unroll
    for (int it = 0; it < 8; ++it) {
        int flat = it * 256 + tid;
        int dp_l = flat >> 6;
        int n_l  = flat & 63;
        float2 v = make_float2(tile[n_l][2*dp_l], tile[n_l][2*dp_l + 1]);
        outp[((size_t)(d0/2 + dp_l) * Bsz + b) * (size_t)Nrows + n0 + n_l] = v;
    }
}

// ---------- unpack: (dp, b, n) float2 -> (b,n,d) f32 ----------
__global__ __launch_bounds__(256) void unpack_kernel(const float2* __restrict__ in,
                                                     float* __restrict__ outp) {
    __shared__ float tile[64][65];
    int tid = threadIdx.x;
    int n0 = blockIdx.x * 64;
    int d0 = blockIdx.y * 64;
    int b  = blockIdx.z;
    #pragma unroll
    for (int it = 0; it < 8; ++it) {
        int flat = it * 256 + tid;
        int dp_l = flat >> 6;
        int n_l  = flat & 63;
        float2 v = in[((size_t)(d0/2 + dp_l) * BATCH + b) * (size_t)NSEQ + n0 + n_l];
        tile[n_l][2*dp_l]     = v.x;
        tile[n_l][2*dp_l + 1] = v.y;
    }
    __syncthreads();
    float* ob = outp + (size_t)b * NSEQ * D;
    #pragma unroll
    for (int it = 0; it < 16; ++it) {
        int n_l = it * 4 + (tid >> 6);
        int d_l = tid & 63;
        ob[(size_t)(n0 + n_l) * D + d0 + d_l] = tile[n_l][d_l];
    }
}

extern "C" void kernel_launch(void* const* d_in, const int* in_sizes, int n_in,
                              void* d_out, int out_size, void* d_ws, size_t ws_size,
                              hipStream_t stream) {
    const float* x = (const float*)d_in[0];   // (4, 4096, 1024)
    const float* t = (const float*)d_in[1];   // (8192, 1024)
    float* outp = (float*)d_out;              // (4, 4096, 1024)

    char* ws = (char*)d_ws;
    float2* wtab = (float2*)ws;                                  // 4096 * 8 = 32 KB (pad to 64 KB)
    float2* tP   = (float2*)(ws + 65536);                        // 512*8192*8 = 32 MB
    const size_t OFF_XP = 65536 + (size_t)NDP * NFFT * sizeof(float2);
    float2* xP   = (float2*)(ws + OFF_XP);                       // 512*4*4096*8 = 64 MB
    const size_t need_full = OFF_XP + (size_t)NDP * BATCH * NSEQ * sizeof(float2);

    wtab_init<<<16, 256, 0, stream>>>(wtab);

    if (ws_size >= need_full) {
        pack_kernel<<<dim3(128, 16, 1), 256, 0, stream>>>(t, tP, NFFT, 1);
        pack_kernel<<<dim3(64, 16, BATCH), 256, 0, stream>>>(x, xP, NSEQ, BATCH);
        conv_kernel<1><<<NDP, NT, 0, stream>>>(xP, tP, nullptr, nullptr, nullptr, wtab);
        unpack_kernel<<<dim3(64, 16, BATCH), 256, 0, stream>>>(xP, outp);
    } else {
        conv_kernel<0><<<NDP, NT, 0, stream>>>(nullptr, nullptr, x, t, outp, wtab);
    }
}

// Round 5
// 406.391 us; speedup vs baseline: 1.3642x; 1.3642x over previous
//
#include <hip/hip_runtime.h>
#include <hip/hip_bf16.h>

#define NFFT 8192
#define NH   4096
#define D    1024
#define NSEQ 4096
#define NDP  512
#define BATCH 4
#define NT   512
#define PI_D 3.14159265358979323846

// 16-pt DFT internal constants
#define C1 0.92387953251128675613f
#define S1 0.38268343236508977173f
#define RT 0.70710678118654752440f

__device__ __forceinline__ int SWZ(int i) { return i ^ ((i >> 4) & 15) ^ ((i >> 8) & 15); }

__device__ __forceinline__ float2 cadd(float2 a, float2 b){ return make_float2(a.x+b.x, a.y+b.y); }
__device__ __forceinline__ float2 csub(float2 a, float2 b){ return make_float2(a.x-b.x, a.y-b.y); }
__device__ __forceinline__ float2 cmul(float2 a, float2 w){ return make_float2(a.x*w.x - a.y*w.y, a.x*w.y + a.y*w.x); }
__device__ __forceinline__ float2 cmulc(float2 a, float2 w){ return make_float2(a.x*w.x + a.y*w.y, a.y*w.x - a.x*w.y); }

// digit-reversal for radices [2,16,16,16] DIF (radix-2 first, stride 4096)
__device__ __forceinline__ int drev16(int k) {
    return ((k & 1) << 12) | (((k >> 1) & 15) << 8) | (((k >> 5) & 15) << 4) | ((k >> 9) & 15);
}
// bank-aware bijection tid(9b) x it(3b) -> k in [0,4096)
__device__ __forceinline__ int kmap16(int tid, int it) {
    return ((tid >> 7) & 3) | (it << 2) | ((tid & 15) << 5) | (((tid >> 4) & 7) << 9);
}

__global__ __launch_bounds__(256) void wtab_init(float2* __restrict__ wtab) {
    int m = blockIdx.x * 256 + threadIdx.x;   // grid 16 -> 4096 entries
    double a = -2.0 * PI_D * (double)m / (double)NFFT;
    wtab[m] = make_float2((float)cos(a), (float)sin(a));
}

// One radix-16 pass over LDS. Thread owns 16 points at stride H within its group.
// Fwd:  read -> DFT16 -> *stage twiddle -> write.
// Inv:  read -> *conj stage twiddle -> IDFT16 -> write.
template<int H, bool TW, bool INV>
__device__ __forceinline__ void pass16(float2* zs, const float2* __restrict__ wt, int t) {
    int blk = t >> 8;
    int i0, tw1i;
    if (H == 256)      { int j = t & 255;                      i0 = blk*4096 + j;           tw1i = 2*j;  }
    else if (H == 16)  { int g = (t>>4) & 15; int j = t & 15;  i0 = blk*4096 + g*256 + j;   tw1i = 32*j; }
    else               { int g = t & 255;                      i0 = blk*4096 + g*16;        tw1i = 0;    }

    float2 w1, w2, w3, w4, w8, w12;
    if (TW) {
        w1 = wt[tw1i];
        w2 = cmul(w1, w1);  w3 = cmul(w2, w1);
        w4 = cmul(w2, w2);  w8 = cmul(w4, w4);  w12 = cmul(w8, w4);
    }

    float2 v[16];
    #pragma unroll
    for (int q = 0; q < 16; ++q) v[q] = zs[SWZ(i0 + H*q)];

    if (INV && TW) {
        v[1]=cmulc(v[1],w1);  v[2]=cmulc(v[2],w2);  v[3]=cmulc(v[3],w3);
        v[4]=cmulc(v[4],w4);  v[5]=cmulc(v[5],cmul(w4,w1));  v[6]=cmulc(v[6],cmul(w4,w2));  v[7]=cmulc(v[7],cmul(w4,w3));
        v[8]=cmulc(v[8],w8);  v[9]=cmulc(v[9],cmul(w8,w1));  v[10]=cmulc(v[10],cmul(w8,w2)); v[11]=cmulc(v[11],cmul(w8,w3));
        v[12]=cmulc(v[12],w12); v[13]=cmulc(v[13],cmul(w12,w1)); v[14]=cmulc(v[14],cmul(w12,w2)); v[15]=cmulc(v[15],cmul(w12,w3));
    }

    // layer 1: groups (v[i], v[i+4], v[i+8], v[i+12]); s[i][o]
    float2 s[4][4];
    #pragma unroll
    for (int i = 0; i < 4; ++i) {
        float2 z0=v[i], z1=v[i+4], z2=v[i+8], z3=v[i+12];
        float2 A=cadd(z0,z2), Cc=csub(z0,z2), B=cadd(z1,z3), Dd=csub(z1,z3);
        s[i][0] = cadd(A,B);
        s[i][2] = csub(A,B);
        if (!INV) { s[i][1] = make_float2(Cc.x+Dd.y, Cc.y-Dd.x);   // C - iD
                    s[i][3] = make_float2(Cc.x-Dd.y, Cc.y+Dd.x); } // C + iD
        else      { s[i][1] = make_float2(Cc.x-Dd.y, Cc.y+Dd.x);
                    s[i][3] = make_float2(Cc.x+Dd.y, Cc.y-Dd.x); }
    }
    // internal twiddles W16^{i*o} (conj for INV)
    if (!INV) {
        s[1][1]=cmul(s[1][1],make_float2(C1,-S1)); s[1][2]=cmul(s[1][2],make_float2(RT,-RT)); s[1][3]=cmul(s[1][3],make_float2(S1,-C1));
        s[2][1]=cmul(s[2][1],make_float2(RT,-RT)); s[2][2]=make_float2(s[2][2].y,-s[2][2].x); s[2][3]=cmul(s[2][3],make_float2(-RT,-RT));
        s[3][1]=cmul(s[3][1],make_float2(S1,-C1)); s[3][2]=cmul(s[3][2],make_float2(-RT,-RT)); s[3][3]=cmul(s[3][3],make_float2(-C1,S1));
    } else {
        s[1][1]=cmul(s[1][1],make_float2(C1,S1));  s[1][2]=cmul(s[1][2],make_float2(RT,RT));  s[1][3]=cmul(s[1][3],make_float2(S1,C1));
        s[2][1]=cmul(s[2][1],make_float2(RT,RT));  s[2][2]=make_float2(-s[2][2].y,s[2][2].x); s[2][3]=cmul(s[2][3],make_float2(-RT,RT));
        s[3][1]=cmul(s[3][1],make_float2(S1,C1));  s[3][2]=cmul(s[3][2],make_float2(-RT,RT)); s[3][3]=cmul(s[3][3],make_float2(-C1,-S1));
    }
    // layer 2: groups (s[0][o], s[1][o], s[2][o], s[3][o]) -> y[o + 4*r2]
    float2 y[16];
    #pragma unroll
    for (int o = 0; o < 4; ++o) {
        float2 z0=s[0][o], z1=s[1][o], z2=s[2][o], z3=s[3][o];
        float2 A=cadd(z0,z2), Cc=csub(z0,z2), B=cadd(z1,z3), Dd=csub(z1,z3);
        y[o]    = cadd(A,B);
        y[o+8]  = csub(A,B);
        if (!INV) { y[o+4]  = make_float2(Cc.x+Dd.y, Cc.y-Dd.x);
                    y[o+12] = make_float2(Cc.x-Dd.y, Cc.y+Dd.x); }
        else      { y[o+4]  = make_float2(Cc.x-Dd.y, Cc.y+Dd.x);
                    y[o+12] = make_float2(Cc.x+Dd.y, Cc.y-Dd.x); }
    }

    if (!INV && TW) {
        y[1]=cmul(y[1],w1);  y[2]=cmul(y[2],w2);  y[3]=cmul(y[3],w3);
        y[4]=cmul(y[4],w4);  y[5]=cmul(y[5],cmul(w4,w1));  y[6]=cmul(y[6],cmul(w4,w2));  y[7]=cmul(y[7],cmul(w4,w3));
        y[8]=cmul(y[8],w8);  y[9]=cmul(y[9],cmul(w8,w1));  y[10]=cmul(y[10],cmul(w8,w2)); y[11]=cmul(y[11],cmul(w8,w3));
        y[12]=cmul(y[12],w12); y[13]=cmul(y[13],cmul(w12,w1)); y[14]=cmul(y[14],cmul(w12,w2)); y[15]=cmul(y[15],cmul(w12,w3));
    }
    #pragma unroll
    for (int r = 0; r < 16; ++r) zs[SWZ(i0 + H*r)] = y[r];
}

// conv: per dp-pair block. Phase 0: t-spectrum into registers. Then loop b=0..3:
// fwd FFT of zero-padded x (radix-2 fused in load), untangle*mul, inv FFT,
// final radix-2 fused with store (only n<4096 needed).
// NOTE: __launch_bounds__(NT, 2) — NOT 4. The (NT,4) variant capped VGPRs at 64
// (observed VGPR_Count=64, FETCH 797MB/WRITE 464MB of scratch spill, VALUBusy 10%).
// LDS (64KB zs) caps residency at 2 blocks/CU regardless, so min-2 loses nothing.
template<int PACKED>
__global__ __launch_bounds__(NT, 2) void conv_kernel(float2* __restrict__ xP,
                                                     const float2* __restrict__ tP,
                                                     const float* __restrict__ xg,
                                                     const float* __restrict__ tg,
                                                     float* __restrict__ outg,
                                                     const float2* __restrict__ wt) {
    __shared__ float2 zs[NFFT];
    int t  = threadIdx.x;
    int dp = blockIdx.x;

    // ---- Phase 0: t spectrum ----
    if (PACKED) {
        const float2* ts = tP + (size_t)dp * NFFT;
        #pragma unroll
        for (int it = 0; it < 8; ++it) {
            int idx = t + it * NT;
            float2 v0 = ts[idx], v1 = ts[idx + NH];
            zs[SWZ(idx)]      = cadd(v0, v1);
            zs[SWZ(idx + NH)] = cmul(csub(v0, v1), wt[idx]);
        }
    } else {
        const float* tb = tg + 2 * dp;
        #pragma unroll
        for (int it = 0; it < 8; ++it) {
            int idx = t + it * NT;
            float2 v0 = *(const float2*)(tb + (size_t)idx * D);
            float2 v1 = *(const float2*)(tb + (size_t)(idx + NH) * D);
            zs[SWZ(idx)]      = cadd(v0, v1);
            zs[SWZ(idx + NH)] = cmul(csub(v0, v1), wt[idx]);
        }
    }
    __syncthreads();
    pass16<256, true,  false>(zs, wt, t); __syncthreads();
    pass16<16,  true,  false>(zs, wt, t); __syncthreads();
    pass16<1,   false, false>(zs, wt, t); __syncthreads();

    float2 T0r[8], T1r[8];
    float2 Tny = make_float2(0.f, 0.f);
    #pragma unroll
    for (int it = 0; it < 8; ++it) {
        int k  = kmap16(t, it);
        int p1 = drev16(k);
        int p2 = drev16((NFFT - k) & (NFFT - 1));
        float2 z1 = zs[SWZ(p1)], z2 = zs[SWZ(p2)];
        T0r[it] = make_float2(0.5f*(z1.x + z2.x), 0.5f*(z1.y - z2.y));
        T1r[it] = make_float2(0.5f*(z1.y + z2.y), 0.5f*(z2.x - z1.x));
    }
    if (t == 0) {   // Nyquist bin k=4096 at position drev16(4096)=8
        float2 zn = zs[SWZ(8)];
        Tny = make_float2(zn.x, zn.y);
    }

    const float sc = 1.0f / (float)NFFT;
    for (int b = 0; b < BATCH; ++b) {
        __syncthreads();   // protect zs against prior-phase readers
        float2* slab = PACKED ? (xP + ((size_t)dp * BATCH + b) * NSEQ) : nullptr;
        if (PACKED) {
            #pragma unroll
            for (int it = 0; it < 8; ++it) {
                int idx = t + it * NT;
                float2 v = slab[idx];
                zs[SWZ(idx)]      = v;                     // x + 0
                zs[SWZ(idx + NH)] = cmul(v, wt[idx]);      // (x - 0)*W^idx
            }
        } else {
            const float* xb = xg + (size_t)b * NSEQ * D + 2 * dp;
            #pragma unroll
            for (int it = 0; it < 8; ++it) {
                int idx = t + it * NT;
                float2 v = *(const float2*)(xb + (size_t)idx * D);
                zs[SWZ(idx)]      = v;
                zs[SWZ(idx + NH)] = cmul(v, wt[idx]);
            }
        }
        __syncthreads();
        pass16<256, true,  false>(zs, wt, t); __syncthreads();
        pass16<16,  true,  false>(zs, wt, t); __syncthreads();
        pass16<1,   false, false>(zs, wt, t); __syncthreads();

        // untangle * multiply * repack (in place, pairwise race-free)
        #pragma unroll
        for (int it = 0; it < 8; ++it) {
            int k  = kmap16(t, it);
            int p1 = drev16(k);
            int p2 = drev16((NFFT - k) & (NFFT - 1));
            float2 z1 = zs[SWZ(p1)], z2 = zs[SWZ(p2)];
            float2 T0 = T0r[it], T1 = T1r[it];
            float x0r = 0.5f*(z1.x + z2.x), x0i = 0.5f*(z1.y - z2.y);
            float x1r = 0.5f*(z1.y + z2.y), x1i = 0.5f*(z2.x - z1.x);
            float y0r = x0r*T0.x - x0i*T0.y, y0i = x0r*T0.y + x0i*T0.x;
            float y1r = x1r*T1.x - x1i*T1.y, y1i = x1r*T1.y + x1i*T1.x;
            zs[SWZ(p1)] = make_float2(y0r - y1i, y0i + y1r);
            zs[SWZ(p2)] = make_float2(y0r + y1i, y1r - y0i);
        }
        if (t == 0) {
            float2 zn = zs[SWZ(8)];
            zs[SWZ(8)] = make_float2(zn.x * Tny.x, zn.y * Tny.y);
        }
        __syncthreads();

        pass16<1,   false, true>(zs, wt, t); __syncthreads();
        pass16<16,  true,  true>(zs, wt, t); __syncthreads();
        pass16<256, true,  true>(zs, wt, t); __syncthreads();

        // final radix-2 (only n < 4096) fused with store
        if (PACKED) {
            #pragma unroll
            for (int it = 0; it < 8; ++it) {
                int n = t + it * NT;
                float2 a  = zs[SWZ(n)];
                float2 bb = zs[SWZ(n + NH)];
                float2 r  = cadd(a, cmulc(bb, wt[n]));
                slab[n] = make_float2(r.x * sc, r.y * sc);
            }
        } else {
            float* ob = outg + (size_t)b * NSEQ * D + 2 * dp;
            #pragma unroll
            for (int it = 0; it < 8; ++it) {
                int n = t + it * NT;
                float2 a  = zs[SWZ(n)];
                float2 bb = zs[SWZ(n + NH)];
                float2 r  = cadd(a, cmulc(bb, wt[n]));
                *(float2*)(ob + (size_t)n * D) = make_float2(r.x * sc, r.y * sc);
            }
        }
    }
}

// ---------- transpose/pack: (b,n,d) f32 -> (dp, b, n) float2 ----------
__global__ __launch_bounds__(256) void pack_kernel(const float* __restrict__ in,
                                                   float2* __restrict__ outp,
                                                   int Nrows, int Bsz) {
    __shared__ float tile[64][65];
    int tid = threadIdx.x;
    int n0 = blockIdx.x * 64;
    int d0 = blockIdx.y * 64;
    int b  = blockIdx.z;
    const float* ib = in + (size_t)b * Nrows * D;
    #pragma unroll
    for (int it = 0; it < 16; ++it) {
        int n_l = it * 4 + (tid >> 6);
        int d_l = tid & 63;
        tile[n_l][d_l] = ib[(size_t)(n0 + n_l) * D + d0 + d_l];
    }
    __syncthreads();
    #pragma unroll
    for (int it = 0; it < 8; ++it) {
        int flat = it * 256 + tid;
        int dp_l = flat >> 6;
        int n_l  = flat & 63;
        float2 v = make_float2(tile[n_l][2*dp_l], tile[n_l][2*dp_l + 1]);
        outp[((size_t)(d0/2 + dp_l) * Bsz + b) * (size_t)Nrows + n0 + n_l] = v;
    }
}

// ---------- unpack: (dp, b, n) float2 -> (b,n,d) f32 ----------
__global__ __launch_bounds__(256) void unpack_kernel(const float2* __restrict__ in,
                                                     float* __restrict__ outp) {
    __shared__ float tile[64][65];
    int tid = threadIdx.x;
    int n0 = blockIdx.x * 64;
    int d0 = blockIdx.y * 64;
    int b  = blockIdx.z;
    #pragma unroll
    for (int it = 0; it < 8; ++it) {
        int flat = it * 256 + tid;
        int dp_l = flat >> 6;
        int n_l  = flat & 63;
        float2 v = in[((size_t)(d0/2 + dp_l) * BATCH + b) * (size_t)NSEQ + n0 + n_l];
        tile[n_l][2*dp_l]     = v.x;
        tile[n_l][2*dp_l + 1] = v.y;
    }
    __syncthreads();
    float* ob = outp + (size_t)b * NSEQ * D;
    #pragma unroll
    for (int it = 0; it < 16; ++it) {
        int n_l = it * 4 + (tid >> 6);
        int d_l = tid & 63;
        ob[(size_t)(n0 + n_l) * D + d0 + d_l] = tile[n_l][d_l];
    }
}

extern "C" void kernel_launch(void* const* d_in, const int* in_sizes, int n_in,
                              void* d_out, int out_size, void* d_ws, size_t ws_size,
                              hipStream_t stream) {
    const float* x = (const float*)d_in[0];   // (4, 4096, 1024)
    const float* t = (const float*)d_in[1];   // (8192, 1024)
    float* outp = (float*)d_out;              // (4, 4096, 1024)

    char* ws = (char*)d_ws;
    float2* wtab = (float2*)ws;                                  // 4096 * 8 = 32 KB (pad to 64 KB)
    float2* tP   = (float2*)(ws + 65536);                        // 512*8192*8 = 32 MB
    const size_t OFF_XP = 65536 + (size_t)NDP * NFFT * sizeof(float2);
    float2* xP   = (float2*)(ws + OFF_XP);                       // 512*4*4096*8 = 64 MB
    const size_t need_full = OFF_XP + (size_t)NDP * BATCH * NSEQ * sizeof(float2);

    wtab_init<<<16, 256, 0, stream>>>(wtab);

    if (ws_size >= need_full) {
        pack_kernel<<<dim3(128, 16, 1), 256, 0, stream>>>(t, tP, NFFT, 1);
        pack_kernel<<<dim3(64, 16, BATCH), 256, 0, stream>>>(x, xP, NSEQ, BATCH);
        conv_kernel<1><<<NDP, NT, 0, stream>>>(xP, tP, nullptr, nullptr, nullptr, wtab);
        unpack_kernel<<<dim3(64, 16, BATCH), 256, 0, stream>>>(xP, outp);
    } else {
        conv_kernel<0><<<NDP, NT, 0, stream>>>(nullptr, nullptr, x, t, outp, wtab);
    }
}

// Round 7
// 187.954 us; speedup vs baseline: 2.9496x; 2.1622x over previous
//
#include <hip/hip_runtime.h>
#include <hip/hip_bf16.h>

#define NFFT 8192
#define NH   4096
#define D    1024
#define NSEQ 4096
#define NDP  512
#define BATCH 4
#define NT   512
#define TSLOT 4097
#define PI_D 3.14159265358979323846

// 16-pt DFT internal constants
#define C1 0.92387953251128675613f
#define S1 0.38268343236508977173f
#define RT 0.70710678118654752440f

__device__ __forceinline__ int SWZ(int i) { return i ^ ((i >> 4) & 15) ^ ((i >> 8) & 15); }

__device__ __forceinline__ float2 cadd(float2 a, float2 b){ return make_float2(a.x+b.x, a.y+b.y); }
__device__ __forceinline__ float2 csub(float2 a, float2 b){ return make_float2(a.x-b.x, a.y-b.y); }
__device__ __forceinline__ float2 cmul(float2 a, float2 w){ return make_float2(a.x*w.x - a.y*w.y, a.x*w.y + a.y*w.x); }
__device__ __forceinline__ float2 cmulc(float2 a, float2 w){ return make_float2(a.x*w.x + a.y*w.y, a.y*w.x - a.x*w.y); }

// digit-reversal for radices [2,16,16,16] DIF (radix-2 first, stride 4096)
__device__ __forceinline__ int drev16(int k) {
    return ((k & 1) << 12) | (((k >> 1) & 15) << 8) | (((k >> 5) & 15) << 4) | ((k >> 9) & 15);
}
// bank-aware bijection tid(9b) x it(3b) -> k in [0,4096)
__device__ __forceinline__ int kmap16(int tid, int it) {
    return ((tid >> 7) & 3) | (it << 2) | ((tid & 15) << 5) | (((tid >> 4) & 7) << 9);
}

__global__ __launch_bounds__(256) void wtab_init(float2* __restrict__ wtab) {
    int m = blockIdx.x * 256 + threadIdx.x;   // grid 16 -> 4096 entries
    double a = -2.0 * PI_D * (double)m / (double)NFFT;
    wtab[m] = make_float2((float)cos(a), (float)sin(a));
}

// One radix-16 pass over LDS. Thread owns 16 points at stride H within its group.
template<int H, bool TW, bool INV>
__device__ __forceinline__ void pass16(float2* zs, const float2* __restrict__ wt, int t) {
    int blk = t >> 8;
    int i0, tw1i;
    if (H == 256)      { int j = t & 255;                      i0 = blk*4096 + j;           tw1i = 2*j;  }
    else if (H == 16)  { int g = (t>>4) & 15; int j = t & 15;  i0 = blk*4096 + g*256 + j;   tw1i = 32*j; }
    else               { int g = t & 255;                      i0 = blk*4096 + g*16;        tw1i = 0;    }

    float2 w1, w2, w3, w4, w8, w12;
    if (TW) {
        w1 = wt[tw1i];
        w2 = cmul(w1, w1);  w3 = cmul(w2, w1);
        w4 = cmul(w2, w2);  w8 = cmul(w4, w4);  w12 = cmul(w8, w4);
    }

    float2 v[16];
    #pragma unroll
    for (int q = 0; q < 16; ++q) v[q] = zs[SWZ(i0 + H*q)];

    if (INV && TW) {
        v[1]=cmulc(v[1],w1);  v[2]=cmulc(v[2],w2);  v[3]=cmulc(v[3],w3);
        v[4]=cmulc(v[4],w4);  v[5]=cmulc(v[5],cmul(w4,w1));  v[6]=cmulc(v[6],cmul(w4,w2));  v[7]=cmulc(v[7],cmul(w4,w3));
        v[8]=cmulc(v[8],w8);  v[9]=cmulc(v[9],cmul(w8,w1));  v[10]=cmulc(v[10],cmul(w8,w2)); v[11]=cmulc(v[11],cmul(w8,w3));
        v[12]=cmulc(v[12],w12); v[13]=cmulc(v[13],cmul(w12,w1)); v[14]=cmulc(v[14],cmul(w12,w2)); v[15]=cmulc(v[15],cmul(w12,w3));
    }

    // layer 1
    float2 s[4][4];
    #pragma unroll
    for (int i = 0; i < 4; ++i) {
        float2 z0=v[i], z1=v[i+4], z2=v[i+8], z3=v[i+12];
        float2 A=cadd(z0,z2), Cc=csub(z0,z2), B=cadd(z1,z3), Dd=csub(z1,z3);
        s[i][0] = cadd(A,B);
        s[i][2] = csub(A,B);
        if (!INV) { s[i][1] = make_float2(Cc.x+Dd.y, Cc.y-Dd.x);
                    s[i][3] = make_float2(Cc.x-Dd.y, Cc.y+Dd.x); }
        else      { s[i][1] = make_float2(Cc.x-Dd.y, Cc.y+Dd.x);
                    s[i][3] = make_float2(Cc.x+Dd.y, Cc.y-Dd.x); }
    }
    // internal twiddles W16^{i*o} (conj for INV)
    if (!INV) {
        s[1][1]=cmul(s[1][1],make_float2(C1,-S1)); s[1][2]=cmul(s[1][2],make_float2(RT,-RT)); s[1][3]=cmul(s[1][3],make_float2(S1,-C1));
        s[2][1]=cmul(s[2][1],make_float2(RT,-RT)); s[2][2]=make_float2(s[2][2].y,-s[2][2].x); s[2][3]=cmul(s[2][3],make_float2(-RT,-RT));
        s[3][1]=cmul(s[3][1],make_float2(S1,-C1)); s[3][2]=cmul(s[3][2],make_float2(-RT,-RT)); s[3][3]=cmul(s[3][3],make_float2(-C1,S1));
    } else {
        s[1][1]=cmul(s[1][1],make_float2(C1,S1));  s[1][2]=cmul(s[1][2],make_float2(RT,RT));  s[1][3]=cmul(s[1][3],make_float2(S1,C1));
        s[2][1]=cmul(s[2][1],make_float2(RT,RT));  s[2][2]=make_float2(-s[2][2].y,s[2][2].x); s[2][3]=cmul(s[2][3],make_float2(-RT,RT));
        s[3][1]=cmul(s[3][1],make_float2(S1,C1));  s[3][2]=cmul(s[3][2],make_float2(-RT,RT)); s[3][3]=cmul(s[3][3],make_float2(-C1,-S1));
    }
    // layer 2
    float2 y[16];
    #pragma unroll
    for (int o = 0; o < 4; ++o) {
        float2 z0=s[0][o], z1=s[1][o], z2=s[2][o], z3=s[3][o];
        float2 A=cadd(z0,z2), Cc=csub(z0,z2), B=cadd(z1,z3), Dd=csub(z1,z3);
        y[o]    = cadd(A,B);
        y[o+8]  = csub(A,B);
        if (!INV) { y[o+4]  = make_float2(Cc.x+Dd.y, Cc.y-Dd.x);
                    y[o+12] = make_float2(Cc.x-Dd.y, Cc.y+Dd.x); }
        else      { y[o+4]  = make_float2(Cc.x-Dd.y, Cc.y+Dd.x);
                    y[o+12] = make_float2(Cc.x+Dd.y, Cc.y-Dd.x); }
    }

    if (!INV && TW) {
        y[1]=cmul(y[1],w1);  y[2]=cmul(y[2],w2);  y[3]=cmul(y[3],w3);
        y[4]=cmul(y[4],w4);  y[5]=cmul(y[5],cmul(w4,w1));  y[6]=cmul(y[6],cmul(w4,w2));  y[7]=cmul(y[7],cmul(w4,w3));
        y[8]=cmul(y[8],w8);  y[9]=cmul(y[9],cmul(w8,w1));  y[10]=cmul(y[10],cmul(w8,w2)); y[11]=cmul(y[11],cmul(w8,w3));
        y[12]=cmul(y[12],w12); y[13]=cmul(y[13],cmul(w12,w1)); y[14]=cmul(y[14],cmul(w12,w2)); y[15]=cmul(y[15],cmul(w12,w3));
    }
    #pragma unroll
    for (int r = 0; r < 16; ++r) zs[SWZ(i0 + H*r)] = y[r];
}

// ---------- tspec: one t-FFT per dp; store untangled (T0,T1) in SLOT order ----------
// slot = it*NT + tid matches conv's enumeration -> both sides fully coalesced.
template<int PACKED>
__global__ __launch_bounds__(NT, 2) void tspec_kernel(const float2* __restrict__ tP,
                                                      const float* __restrict__ tg,
                                                      const float2* __restrict__ wt,
                                                      float4* __restrict__ tspecU) {
    __shared__ float2 zs[NFFT];
    int t  = threadIdx.x;
    int dp = blockIdx.x;

    if (PACKED) {
        const float2* slab = tP + (size_t)dp * NFFT;
        #pragma unroll
        for (int it = 0; it < 8; ++it) {
            int idx = t + it * NT;
            float2 v0 = slab[idx], v1 = slab[idx + NH];
            zs[SWZ(idx)]      = cadd(v0, v1);
            zs[SWZ(idx + NH)] = cmul(csub(v0, v1), wt[idx]);
        }
    } else {
        const float* tb = tg + 2 * dp;
        #pragma unroll
        for (int it = 0; it < 8; ++it) {
            int idx = t + it * NT;
            float2 v0 = *(const float2*)(tb + (size_t)idx * D);
            float2 v1 = *(const float2*)(tb + (size_t)(idx + NH) * D);
            zs[SWZ(idx)]      = cadd(v0, v1);
            zs[SWZ(idx + NH)] = cmul(csub(v0, v1), wt[idx]);
        }
    }
    __syncthreads();
    pass16<256, true,  false>(zs, wt, t); __syncthreads();
    pass16<16,  true,  false>(zs, wt, t); __syncthreads();
    pass16<1,   false, false>(zs, wt, t); __syncthreads();

    float4* o = tspecU + (size_t)dp * TSLOT;
    #pragma unroll
    for (int it = 0; it < 8; ++it) {
        int k  = kmap16(t, it);
        int p1 = drev16(k);
        int p2 = drev16((NFFT - k) & (NFFT - 1));
        float2 z1 = zs[SWZ(p1)], z2 = zs[SWZ(p2)];
        o[it * NT + t] = make_float4(0.5f*(z1.x + z2.x), 0.5f*(z1.y - z2.y),
                                     0.5f*(z1.y + z2.y), 0.5f*(z2.x - z1.x));
    }
    if (t == 0) {   // Nyquist bin k=4096 at position drev16(4096)=8
        float2 zn = zs[SWZ(8)];
        o[4096] = make_float4(zn.x, 0.f, zn.y, 0.f);
    }
}

// ---------- conv: grid (NDP, BATCH); fwd FFT, untangle*mul (T streamed), inv FFT ----------
template<int PACKED>
__global__ __launch_bounds__(NT, 2) void conv_kernel(float2* __restrict__ xP,
                                                     const float* __restrict__ xg,
                                                     float* __restrict__ outg,
                                                     const float2* __restrict__ wt,
                                                     const float4* __restrict__ tspecU) {
    __shared__ float2 zs[NFFT];
    int t  = threadIdx.x;
    int dp = blockIdx.x;
    int b  = blockIdx.y;

    float2* slab = PACKED ? (xP + ((size_t)dp * BATCH + b) * NSEQ) : nullptr;
    if (PACKED) {
        #pragma unroll
        for (int it = 0; it < 8; ++it) {
            int idx = t + it * NT;
            float2 v = slab[idx];
            zs[SWZ(idx)]      = v;                     // x + 0
            zs[SWZ(idx + NH)] = cmul(v, wt[idx]);      // (x - 0)*W^idx
        }
    } else {
        const float* xb = xg + (size_t)b * NSEQ * D + 2 * dp;
        #pragma unroll
        for (int it = 0; it < 8; ++it) {
            int idx = t + it * NT;
            float2 v = *(const float2*)(xb + (size_t)idx * D);
            zs[SWZ(idx)]      = v;
            zs[SWZ(idx + NH)] = cmul(v, wt[idx]);
        }
    }
    __syncthreads();
    pass16<256, true,  false>(zs, wt, t); __syncthreads();
    pass16<16,  true,  false>(zs, wt, t); __syncthreads();
    pass16<1,   false, false>(zs, wt, t); __syncthreads();

    // untangle * multiply * repack (T streamed from slot-ordered tspecU, coalesced)
    const float4* ts4 = tspecU + (size_t)dp * TSLOT;
    #pragma unroll
    for (int it = 0; it < 8; ++it) {
        int k  = kmap16(t, it);
        int p1 = drev16(k);
        int p2 = drev16((NFFT - k) & (NFFT - 1));
        float2 z1 = zs[SWZ(p1)], z2 = zs[SWZ(p2)];
        float4 T  = ts4[it * NT + t];
        float x0r = 0.5f*(z1.x + z2.x), x0i = 0.5f*(z1.y - z2.y);
        float x1r = 0.5f*(z1.y + z2.y), x1i = 0.5f*(z2.x - z1.x);
        float y0r = x0r*T.x - x0i*T.y, y0i = x0r*T.y + x0i*T.x;
        float y1r = x1r*T.z - x1i*T.w, y1i = x1r*T.w + x1i*T.z;
        zs[SWZ(p1)] = make_float2(y0r - y1i, y0i + y1r);
        zs[SWZ(p2)] = make_float2(y0r + y1i, y1r - y0i);
    }
    if (t == 0) {
        float4 T = ts4[4096];
        float2 zn = zs[SWZ(8)];
        zs[SWZ(8)] = make_float2(zn.x * T.x, zn.y * T.z);
    }
    __syncthreads();

    pass16<1,   false, true>(zs, wt, t); __syncthreads();
    pass16<16,  true,  true>(zs, wt, t); __syncthreads();
    pass16<256, true,  true>(zs, wt, t); __syncthreads();

    // final radix-2 (only n < 4096) fused with store
    const float sc = 1.0f / (float)NFFT;
    if (PACKED) {
        #pragma unroll
        for (int it = 0; it < 8; ++it) {
            int n = t + it * NT;
            float2 a  = zs[SWZ(n)];
            float2 bb = zs[SWZ(n + NH)];
            float2 r  = cadd(a, cmulc(bb, wt[n]));
            slab[n] = make_float2(r.x * sc, r.y * sc);
        }
    } else {
        float* ob = outg + (size_t)b * NSEQ * D + 2 * dp;
        #pragma unroll
        for (int it = 0; it < 8; ++it) {
            int n = t + it * NT;
            float2 a  = zs[SWZ(n)];
            float2 bb = zs[SWZ(n + NH)];
            float2 r  = cadd(a, cmulc(bb, wt[n]));
            *(float2*)(ob + (size_t)n * D) = make_float2(r.x * sc, r.y * sc);
        }
    }
}

// ---------- transpose/pack: (b,n,d) f32 -> (dp, b, n) float2 ----------
__global__ __launch_bounds__(256) void pack_kernel(const float* __restrict__ in,
                                                   float2* __restrict__ outp,
                                                   int Nrows, int Bsz) {
    __shared__ float tile[64][65];
    int tid = threadIdx.x;
    int n0 = blockIdx.x * 64;
    int d0 = blockIdx.y * 64;
    int b  = blockIdx.z;
    const float* ib = in + (size_t)b * Nrows * D;
    #pragma unroll
    for (int it = 0; it < 16; ++it) {
        int n_l = it * 4 + (tid >> 6);
        int d_l = tid & 63;
        tile[n_l][d_l] = ib[(size_t)(n0 + n_l) * D + d0 + d_l];
    }
    __syncthreads();
    #pragma unroll
    for (int it = 0; it < 8; ++it) {
        int flat = it * 256 + tid;
        int dp_l = flat >> 6;
        int n_l  = flat & 63;
        float2 v = make_float2(tile[n_l][2*dp_l], tile[n_l][2*dp_l + 1]);
        outp[((size_t)(d0/2 + dp_l) * Bsz + b) * (size_t)Nrows + n0 + n_l] = v;
    }
}

// ---------- unpack: (dp, b, n) float2 -> (b,n,d) f32 ----------
__global__ __launch_bounds__(256) void unpack_kernel(const float2* __restrict__ in,
                                                     float* __restrict__ outp) {
    __shared__ float tile[64][65];
    int tid = threadIdx.x;
    int n0 = blockIdx.x * 64;
    int d0 = blockIdx.y * 64;
    int b  = blockIdx.z;
    #pragma unroll
    for (int it = 0; it < 8; ++it) {
        int flat = it * 256 + tid;
        int dp_l = flat >> 6;
        int n_l  = flat & 63;
        float2 v = in[((size_t)(d0/2 + dp_l) * BATCH + b) * (size_t)NSEQ + n0 + n_l];
        tile[n_l][2*dp_l]     = v.x;
        tile[n_l][2*dp_l + 1] = v.y;
    }
    __syncthreads();
    float* ob = outp + (size_t)b * NSEQ * D;
    #pragma unroll
    for (int it = 0; it < 16; ++it) {
        int n_l = it * 4 + (tid >> 6);
        int d_l = tid & 63;
        ob[(size_t)(n0 + n_l) * D + d0 + d_l] = tile[n_l][d_l];
    }
}

extern "C" void kernel_launch(void* const* d_in, const int* in_sizes, int n_in,
                              void* d_out, int out_size, void* d_ws, size_t ws_size,
                              hipStream_t stream) {
    const float* x = (const float*)d_in[0];   // (4, 4096, 1024)
    const float* t = (const float*)d_in[1];   // (8192, 1024)
    float* outp = (float*)d_out;              // (4, 4096, 1024)

    char* ws = (char*)d_ws;
    float2* wtab   = (float2*)ws;                                   // 32 KB used, 64 KB reserved
    float4* tspecU = (float4*)(ws + 65536);                         // 512*4097*16 = 33,562,624
    const size_t OFF_REGION = 65536 + (size_t)NDP * TSLOT * 16;     // 33,628,160
    float2* region = (float2*)(ws + OFF_REGION);                    // tP (32 MB) then xP (64 MB)
    const size_t need_full = OFF_REGION + (size_t)NDP * BATCH * NSEQ * sizeof(float2);

    wtab_init<<<16, 256, 0, stream>>>(wtab);

    if (ws_size >= need_full) {
        // pack t -> region; t-spectra -> tspecU; then reuse region for x
        pack_kernel<<<dim3(128, 16, 1), 256, 0, stream>>>(t, region, NFFT, 1);
        tspec_kernel<1><<<NDP, NT, 0, stream>>>(region, nullptr, wtab, tspecU);
        pack_kernel<<<dim3(64, 16, BATCH), 256, 0, stream>>>(x, region, NSEQ, BATCH);
        conv_kernel<1><<<dim3(NDP, BATCH, 1), NT, 0, stream>>>(region, nullptr, nullptr, wtab, tspecU);
        unpack_kernel<<<dim3(64, 16, BATCH), 256, 0, stream>>>(region, outp);
    } else {
        // strided fallback (needs only ~33.7 MB, proven by round-1)
        tspec_kernel<0><<<NDP, NT, 0, stream>>>(nullptr, t, wtab, tspecU);
        conv_kernel<0><<<dim3(NDP, BATCH, 1), NT, 0, stream>>>(nullptr, x, outp, wtab, tspecU);
    }
}